// Round 3
// baseline (622.343 us; speedup 1.0000x reference)
//
#include <hip/hip_runtime.h>
#include <stdint.h>

#define BDIM 2048
#define KDIM 768
#define NTOT 16140
#define SROW 16160   // padded fp16-logit row stride (x2B = 32320 B, 64B-aligned rows)

typedef _Float16 half8 __attribute__((ext_vector_type(8)));
typedef float floatx4 __attribute__((ext_vector_type(4)));

__device__ __forceinline__ _Float16 f2h(float f) { return (_Float16)f; }
__device__ __forceinline__ float h2f(unsigned short u) {
  return (float)__builtin_bit_cast(_Float16, u);
}

__device__ __forceinline__ uint4 pack8(float4 a, float4 b) {
  half8 h;
  h[0] = f2h(a.x); h[1] = f2h(a.y); h[2] = f2h(a.z); h[3] = f2h(a.w);
  h[4] = f2h(b.x); h[5] = f2h(b.y); h[6] = f2h(b.z); h[7] = f2h(b.w);
  return __builtin_bit_cast(uint4, h);
}

// ---------------- fp32 -> fp16 conversion of x only (3 MB, L2-resident operand) ----------------
__global__ __launch_bounds__(256) void xconvert_kernel(
    const float* __restrict__ x, unsigned short* __restrict__ xh)
{
  int i4 = blockIdx.x * 256 + threadIdx.x;   // 393216 threads, 4 elems each
  float4 v = reinterpret_cast<const float4*>(x)[i4];
  half8 dummy;
  ushort4 o;
  o.x = __builtin_bit_cast(unsigned short, f2h(v.x));
  o.y = __builtin_bit_cast(unsigned short, f2h(v.y));
  o.z = __builtin_bit_cast(unsigned short, f2h(v.z));
  o.w = __builtin_bit_cast(unsigned short, f2h(v.w));
  reinterpret_cast<ushort4*>(xh)[i4] = o;
  (void)dummy;
}

// ---------------- fp16 MFMA GEMM: logits16[row][col] = x @ Wcat^T (padded row-major fp16) -------
#define LSTRIDE 7      // uint4 per 32-k row (112 B: 16B-aligned, 2-way bank alias = free)
#define EPI_STRIDE 132 // floats per staged C row

__device__ __forceinline__ const float* wrow(
    int bcol,
    const float* W0, const float* W1, const float* W2,
    const float* W3, const float* W4, const float* W5)
{
  const float* base; int cb;
  if      (bcol < 20)   { base = W0; cb = 0; }
  else if (bcol < 90)   { base = W1; cb = 20; }
  else if (bcol < 340)  { base = W2; cb = 90; }
  else if (bcol < 1140) { base = W3; cb = 340; }
  else if (bcol < 4140) { base = W4; cb = 1140; }
  else                  { base = W5; cb = 4140; }
  return base + (long long)(bcol - cb) * KDIM;
}

__global__ __launch_bounds__(256, 2) void gemm_kernel(
    const unsigned short* __restrict__ Ah,   // [2048][768] fp16
    const float* __restrict__ W0, const float* __restrict__ W1,
    const float* __restrict__ W2, const float* __restrict__ W3,
    const float* __restrict__ W4, const float* __restrict__ W5,
    unsigned short* __restrict__ logits)     // [2048][SROW] fp16
{
  __shared__ __align__(16) char smem_raw[64 * EPI_STRIDE * 4];  // 33792 B (stage ∪ epilogue)
  uint4* lA = (uint4*)smem_raw;
  uint4* lB = lA + 128 * LSTRIDE;
  float* epi = (float*)smem_raw;

  // XCD swizzle: bid%8 = XCD; each XCD owns a contiguous run of col-tiles, row-tile fastest.
  const int bid = blockIdx.x;                 // 2032 = 8 * 254
  const int logical = (bid & 7) * 254 + (bid >> 3);
  const int cx = logical >> 4;                // col tile 0..126
  const int row0 = (logical & 15) * 128;
  const int col0 = cx * 128;

  const int tid  = threadIdx.x;
  const int wave = tid >> 6;
  const int lane = tid & 63;
  const int wr = (wave >> 1) * 64;
  const int wc = (wave & 1) * 64;
  const int q  = lane >> 4;
  const int lr = lane & 15;
  const int srow = tid >> 2;   // staging row 0..63
  const int sk   = tid & 3;    // staging uint4 slot

  floatx4 acc[4][4];
#pragma unroll
  for (int i = 0; i < 4; ++i)
#pragma unroll
    for (int j = 0; j < 4; ++j)
      acc[i][j] = (floatx4){0.f, 0.f, 0.f, 0.f};

  uint4 ra[2];
  float4 rw0[2], rw1[2];
#pragma unroll
  for (int r = 0; r < 2; ++r) {
    int arow = row0 + r * 64 + srow;
    ra[r] = reinterpret_cast<const uint4*>(Ah + (long long)arow * KDIM)[sk];
    int bcol = col0 + r * 64 + srow;
    if (bcol >= NTOT) bcol = NTOT - 1;
    const float* wp = wrow(bcol, W0, W1, W2, W3, W4, W5);
    rw0[r] = reinterpret_cast<const float4*>(wp)[sk * 2];
    rw1[r] = reinterpret_cast<const float4*>(wp)[sk * 2 + 1];
  }

  for (int kt = 0; kt < KDIM / 32; ++kt) {
    __syncthreads();
#pragma unroll
    for (int r = 0; r < 2; ++r) {
      lA[(r * 64 + srow) * LSTRIDE + sk] = ra[r];
      lB[(r * 64 + srow) * LSTRIDE + sk] = pack8(rw0[r], rw1[r]);
    }
    if (kt + 1 < KDIM / 32) {
      const int kb = (kt + 1) * 32;
#pragma unroll
      for (int r = 0; r < 2; ++r) {
        int arow = row0 + r * 64 + srow;
        ra[r] = reinterpret_cast<const uint4*>(Ah + (long long)arow * KDIM + kb)[sk];
        int bcol = col0 + r * 64 + srow;
        if (bcol >= NTOT) bcol = NTOT - 1;
        const float* wp = wrow(bcol, W0, W1, W2, W3, W4, W5) + kb;
        rw0[r] = reinterpret_cast<const float4*>(wp)[sk * 2];
        rw1[r] = reinterpret_cast<const float4*>(wp)[sk * 2 + 1];
      }
    }
    __syncthreads();
    half8 af[4], bf[4];
#pragma unroll
    for (int i = 0; i < 4; ++i)
      af[i] = __builtin_bit_cast(half8, lA[(wr + i * 16 + lr) * LSTRIDE + q]);
#pragma unroll
    for (int j = 0; j < 4; ++j)
      bf[j] = __builtin_bit_cast(half8, lB[(wc + j * 16 + lr) * LSTRIDE + q]);
#pragma unroll
    for (int i = 0; i < 4; ++i)
#pragma unroll
      for (int j = 0; j < 4; ++j)
        acc[i][j] = __builtin_amdgcn_mfma_f32_16x16x32_f16(af[i], bf[j], acc[i][j], 0, 0, 0);
  }

  // ---- epilogue: stage fp32 tile in LDS, emit fp16 full-line ushort8 rows ----
  for (int h = 0; h < 2; ++h) {
    __syncthreads();
    if ((wave >> 1) == h) {
#pragma unroll
      for (int i = 0; i < 4; ++i)
#pragma unroll
        for (int j = 0; j < 4; ++j)
#pragma unroll
          for (int rg = 0; rg < 4; ++rg)
            epi[(i * 16 + q * 4 + rg) * EPI_STRIDE + wc + j * 16 + lr] = acc[i][j][rg];
    }
    __syncthreads();
#pragma unroll
    for (int it = 0; it < 4; ++it) {
      int idx = it * 256 + tid;
      int r = idx >> 4, v = idx & 15;
      int col = col0 + v * 8;
      if (col + 8 <= SROW) {   // only last col-tile masks (pad cols 16140..16159 hold garbage)
        float4 a = *(const float4*)(epi + r * EPI_STRIDE + v * 8);
        float4 b = *(const float4*)(epi + r * EPI_STRIDE + v * 8 + 4);
        *(uint4*)(logits + (long long)(row0 + h * 64 + r) * SROW + col) = pack8(a, b);
      }
    }
  }
}

// ---------------- fused 6-level tree softmax: child-parallel, LDS atomic segment sums ----------
__global__ __launch_bounds__(256) void tree_softmax_kernel(
    const unsigned short* __restrict__ logits,   // [2048][SROW] fp16
    float* __restrict__ out,
    const float* __restrict__ b0, const float* __restrict__ b1, const float* __restrict__ b2,
    const float* __restrict__ b3, const float* __restrict__ b4, const float* __restrict__ b5,
    const int* __restrict__ p1, const int* __restrict__ p2, const int* __restrict__ p3,
    const int* __restrict__ p4, const int* __restrict__ p5)
{
  __shared__ float bufs[3][3000];   // 36 KB: prev-probs, curr-probs, segment sums
  float* pv = bufs[0];
  float* cr = bufs[1];
  float* sm = bufs[2];

  const int tid = threadIdx.x;
  const int row = blockIdx.x;
  const unsigned short* lrow = logits + (long long)row * SROW;

  const float* bias[6] = {b0, b1, b2, b3, b4, b5};
  const int* par[6] = {nullptr, p1, p2, p3, p4, p5};
  const int Cn[6] = {20, 70, 250, 800, 3000, 12000};
  const int Pn[6] = {1, 20, 70, 250, 800, 3000};
  const int lb[6] = {0, 20, 90, 340, 1140, 4140};
  const long long ob[6] = {0, 40960, 184320, 696320, 2334720, 8478720};

  for (int L = 0; L < 6; ++L) {
    for (int s = tid; s < Pn[L]; s += 256) sm[s] = 0.f;
    __syncthreads();
    // pass 1: exp + segment-sum via LDS atomics (children of a parent are contiguous)
    for (int c = tid; c < Cn[L]; c += 256) {
      float l = h2f(lrow[lb[L] + c]) + bias[L][c];
      float e = __expf(l);                       // logits ~N(0,1): no max-subtract needed
      int p = (L == 0) ? 0 : par[L][c];
      atomicAdd(&sm[p], e);
    }
    __syncthreads();
    // pass 2: recompute e (L2-hot re-read; cheaper than register stash), scale, emit
    float* dst = out + ob[L] + (long long)row * Cn[L];
    for (int c = tid; c < Cn[L]; c += 256) {
      float l = h2f(lrow[lb[L] + c]) + bias[L][c];
      float e = __expf(l);
      int p = (L == 0) ? 0 : par[L][c];
      float pp = (L == 0) ? 1.0f : pv[p];
      float val = e * pp / sm[p];
      dst[c] = val;
      if (L < 5) cr[c] = val;
    }
    __syncthreads();
    float* t = pv; pv = cr; cr = t;
  }
}

extern "C" void kernel_launch(void* const* d_in, const int* in_sizes, int n_in,
                              void* d_out, int out_size, void* d_ws, size_t ws_size,
                              hipStream_t stream)
{
  const float* x = (const float*)d_in[0];
  const float* W[6]    = {(const float*)d_in[1], (const float*)d_in[3], (const float*)d_in[5],
                          (const float*)d_in[7], (const float*)d_in[9], (const float*)d_in[11]};
  const float* bias[6] = {(const float*)d_in[2], (const float*)d_in[4], (const float*)d_in[6],
                          (const float*)d_in[8], (const float*)d_in[10], (const float*)d_in[12]};
  const int* p[5] = {(const int*)d_in[13], (const int*)d_in[14], (const int*)d_in[15],
                     (const int*)d_in[16], (const int*)d_in[17]};
  float* out = (float*)d_out;
  char* ws = (char*)d_ws;
  unsigned short* logits = (unsigned short*)ws;               // 2048*16160*2 = 66,191,360 B
  unsigned short* xh = (unsigned short*)(ws + 66191360);      // 3,145,728 B

  xconvert_kernel<<<1536, 256, 0, stream>>>(x, xh);
  gemm_kernel<<<2032, 256, 0, stream>>>(xh, W[0], W[1], W[2], W[3], W[4], W[5], logits);
  tree_softmax_kernel<<<2048, 256, 0, stream>>>(
      logits, out, bias[0], bias[1], bias[2], bias[3], bias[4], bias[5],
      p[0], p[1], p[2], p[3], p[4]);
}